// Round 8
// baseline (664.392 us; speedup 1.0000x reference)
//
#include <hip/hip_runtime.h>

#define EMB 128
#define HRANGE 16384       // nodes per histogram range (64 KB LDS, packed cnt|deg)
#define HSTRIPE_LOG 13     // 8192 edges per stripe
#define UN 4

typedef __attribute__((ext_vector_type(8))) short bf16x8;
typedef __attribute__((ext_vector_type(4))) float f32x4;

__device__ inline unsigned short f2bf(float f) {
  unsigned u = __float_as_uint(f);
  return (unsigned short)((u + 0x7FFF + ((u >> 16) & 1)) >> 16);   // RNE
}
__device__ inline float bf2f(unsigned short s) {
  return __uint_as_float(((unsigned)s) << 16);
}

// ---------- CSR build via LDS histograms, packed cnt|deg (no global atomics) ----
__global__ __launch_bounds__(256) void k_hist(const int* __restrict__ row,
    const int* __restrict__ col, unsigned short* __restrict__ degP,
    unsigned short* __restrict__ cntP, int* __restrict__ ord, int E, int N) {
  __shared__ unsigned int hw[HRANGE];
  int s = blockIdx.x, r = blockIdx.y;
  int nlo = r * HRANGE;
  for (int t = threadIdx.x; t < HRANGE; t += 256) hw[t] = 0u;
  __syncthreads();
  int k0 = s << HSTRIPE_LOG;
  int k1 = min(E, k0 + (1 << HSTRIPE_LOG));
  for (int k = k0 + threadIdx.x; k < k1; k += 256) {
    int c = col[k] - nlo;
    if ((unsigned)c < HRANGE)
      ord[k] = (int)(atomicAdd(&hw[c], 1u) & 0xFFFFu);
    int rr = row[k] - nlo;
    if ((unsigned)rr < HRANGE)
      atomicAdd(&hw[rr], 0x10000u);
  }
  __syncthreads();
  for (int t = threadIdx.x; t < HRANGE; t += 256) {
    int node = nlo + t;
    if (node < N) {
      unsigned w = hw[t];
      cntP[(size_t)s * N + node] = (unsigned short)(w & 0xFFFFu);
      degP[(size_t)s * N + node] = (unsigned short)(w >> 16);
    }
  }
}

// exclusive prefix over stripes per node (in place, u16); cnt[i] = total
__global__ __launch_bounds__(256) void k_colreduce(unsigned short* __restrict__ cntP,
    int* __restrict__ cnt, int N, int ns) {
  int i = blockIdx.x * 256 + threadIdx.x;
  if (i < N) {
    int ssum = 0;
    for (int s = 0; s < ns; ++s) {
      int v = cntP[(size_t)s * N + i];
      cntP[(size_t)s * N + i] = (unsigned short)ssum;
      ssum += v;
    }
    cnt[i] = ssum;
  }
}

// deg[i] = sum of degP over stripes; dinv = rsqrt(max(deg,1))
__global__ __launch_bounds__(256) void k_dinv(const unsigned short* __restrict__ degP,
    float* __restrict__ dinv, int N, int ns) {
  int i = blockIdx.x * 256 + threadIdx.x;
  if (i < N) {
    int d = 0;
    for (int s = 0; s < ns; ++s) d += degP[(size_t)s * N + i];
    float df = (float)(d == 0 ? 1 : d);
    dinv[i] = 1.0f / sqrtf(df);
  }
}

// ---------- multi-block exclusive scan ----------
__global__ __launch_bounds__(256) void k_scan_local(const int* __restrict__ cnt,
    int* __restrict__ startp, int* __restrict__ partial, int N) {
  __shared__ int lds[256];
  int tid = threadIdx.x;
  int i = blockIdx.x * 256 + tid;
  int v = (i < N) ? cnt[i] : 0;
  lds[tid] = v;
  __syncthreads();
#pragma unroll
  for (int off = 1; off < 256; off <<= 1) {
    int t = (tid >= off) ? lds[tid - off] : 0;
    __syncthreads();
    lds[tid] += t;
    __syncthreads();
  }
  if (i < N) startp[i] = lds[tid] - v;
  if (tid == 255) partial[blockIdx.x] = lds[255];
}

__global__ void k_scan_part(int* __restrict__ partial, int nb) {
  __shared__ int lds[1024];
  int tid = threadIdx.x;
  int v = (tid < nb) ? partial[tid] : 0;
  lds[tid] = v;
  __syncthreads();
  for (int off = 1; off < 1024; off <<= 1) {
    int t = (tid >= off) ? lds[tid - off] : 0;
    __syncthreads();
    lds[tid] += t;
    __syncthreads();
  }
  if (tid < nb) partial[tid] = lds[tid] - v;
}

__global__ __launch_bounds__(256) void k_scan_add(int* __restrict__ startp,
    const int* __restrict__ partial, int N, int E) {
  int i = blockIdx.x * 256 + threadIdx.x;
  if (i < N) startp[i] += partial[blockIdx.x];
  if (i == 0) startp[N] = E;
}

__global__ __launch_bounds__(256) void k_fill(const int* __restrict__ row,
    const int* __restrict__ col, const int* __restrict__ attr,
    const int* __restrict__ startp, const unsigned short* __restrict__ cntP,
    const int* __restrict__ ord, const float* __restrict__ dinv,
    int2* __restrict__ emeta, int E, int N) {
  int k = blockIdx.x * 256 + threadIdx.x;
  if (k < E) {
    int r = row[k], c = col[k];
    int s = k >> HSTRIPE_LOG;
    int pos = startp[c] + (int)cntP[(size_t)s * N + c] + ord[k];
    int2 m;
    m.x = r | (attr[k] << 20);
    m.y = __float_as_int(dinv[r] * dinv[c]);
    emeta[pos] = m;
  }
}

// ---------- W split: Wt[l][ 0..127 ][k]=hi, Wt[l][128..255][k]=lo (col-major) ----
__global__ __launch_bounds__(256) void k_wsplit(const float* __restrict__ W,
    unsigned short* __restrict__ Wt, int total) {
  int t = blockIdx.x * 256 + threadIdx.x;   // t = (l*128 + k)*128 + n
  if (t >= total) return;
  int n = t & 127, k = (t >> 7) & 127, l = t >> 14;
  float v = W[t];
  unsigned short hi = f2bf(v);
  unsigned short lo = f2bf(v - bf2f(hi));
  size_t base = (size_t)l * 256 * EMB;
  Wt[base + (size_t)n * EMB + k] = hi;
  Wt[base + (size_t)(128 + n) * EMB + k] = lo;
}

// ---------- fused layer: gather-aggregate -> LDS (split bf16) -> MFMA GEMM ----
// Block = 128 dest nodes, 4 waves. Agg: wave w handles nodes w*32..w*32+31,
// half-wave per edge (32 lanes x float4 = full 512B h row), UN pair-steps in
// flight. As rows stored XOR-swizzled ((row&7)<<4) to kill 256B-stride bank
// conflicts on the MFMA fragment reads. L0: gather atom_emb[x[src]] directly
// (both L2-resident) instead of materialized h.
template<int L0>
__global__ __launch_bounds__(256) void k_fused(const float* __restrict__ h,
    const int* __restrict__ xv, const float* __restrict__ atom_emb,
    const int* __restrict__ startp, const int2* __restrict__ emeta,
    const float* __restrict__ bond_emb, const unsigned short* __restrict__ Wt,
    const float* __restrict__ bias, float* __restrict__ outp, int N, int BV) {
  __shared__ char AsH[128 * 256];    // 32 KB  [128 rows][128 bf16]
  __shared__ char AsL[128 * 256];    // 32 KB
  __shared__ float eb_lds[16 * EMB]; // 8 KB bond table
  for (int t = threadIdx.x; t < BV * (EMB / 4); t += 256)
    reinterpret_cast<float4*>(eb_lds)[t] =
        reinterpret_cast<const float4*>(bond_emb)[t];
  __syncthreads();

  int wave = threadIdx.x >> 6, lane = threadIdx.x & 63;
  int half = lane >> 5, sl = lane & 31;
  int blockbase = blockIdx.x * 128;

  for (int it = 0; it < 32; ++it) {
    int nloc = wave * 32 + it;
    int node = blockbase + nloc;
    float4 acc = make_float4(0.f, 0.f, 0.f, 0.f);
    if (node < N) {
      int s = startp[node], e = startp[node + 1];
      int npair = (e - s + 1) >> 1;
      for (int step = 0; step < npair; step += UN) {
        int2 m[UN];
#pragma unroll
        for (int u = 0; u < UN; ++u) {
          int ep = s + 2 * (step + u) + half;
          m[u] = (ep < e) ? emeta[ep] : make_int2(0, 0);   // pad: w=+0 -> adds 0
        }
        float4 hv[UN];
#pragma unroll
        for (int u = 0; u < UN; ++u) {
          int src = m[u].x & 0xFFFFF;
          if constexpr (L0) {
            int xi = xv[src];
            hv[u] = *(reinterpret_cast<const float4*>(atom_emb + (size_t)xi * EMB) + sl);
          } else {
            hv[u] = *(reinterpret_cast<const float4*>(h + (size_t)src * EMB) + sl);
          }
        }
#pragma unroll
        for (int u = 0; u < UN; ++u) {
          float w = __int_as_float(m[u].y);
          float4 ev = *(reinterpret_cast<const float4*>(eb_lds + (m[u].x >> 20) * EMB) + sl);
          acc.x = fmaf(w * hv[u].x, ev.x, acc.x);
          acc.y = fmaf(w * hv[u].y, ev.y, acc.y);
          acc.z = fmaf(w * hv[u].z, ev.z, acc.z);
          acc.w = fmaf(w * hv[u].w, ev.w, acc.w);
        }
      }
      acc.x += __shfl_xor(acc.x, 32);
      acc.y += __shfl_xor(acc.y, 32);
      acc.z += __shfl_xor(acc.z, 32);
      acc.w += __shfl_xor(acc.w, 32);
    }
    if (half == 0) {   // node>=N leaves acc=0 -> clean zero rows in As
      unsigned short h0 = f2bf(acc.x), h1 = f2bf(acc.y);
      unsigned short h2 = f2bf(acc.z), h3 = f2bf(acc.w);
      ushort4 hi4; hi4.x = h0; hi4.y = h1; hi4.z = h2; hi4.w = h3;
      ushort4 lo4;
      lo4.x = f2bf(acc.x - bf2f(h0));
      lo4.y = f2bf(acc.y - bf2f(h1));
      lo4.z = f2bf(acc.z - bf2f(h2));
      lo4.w = f2bf(acc.w - bf2f(h3));
      unsigned off = ((unsigned)(nloc * 256 + sl * 8)) ^ (((unsigned)nloc & 7u) << 4);
      *reinterpret_cast<ushort4*>(AsH + off) = hi4;
      *reinterpret_cast<ushort4*>(AsL + off) = lo4;
    }
  }
  __syncthreads();

  // MFMA phase: wave computes rows [wave*32, wave*32+32) x all 128 cols
  int lr = lane & 15, lg = lane >> 4;
  int rowloc = wave * 32;
  f32x4 acc2[2][8];
#pragma unroll
  for (int m = 0; m < 2; ++m)
#pragma unroll
    for (int n = 0; n < 8; ++n) acc2[m][n] = (f32x4){0.f, 0.f, 0.f, 0.f};

#pragma unroll
  for (int kb = 0; kb < 4; ++kb) {
    int koff = kb * 32 + lg * 8;
    bf16x8 ah[2], al[2];
#pragma unroll
    for (int m = 0; m < 2; ++m) {
      int rloc = rowloc + m * 16 + lr;
      unsigned off = ((unsigned)(rloc * 256 + koff * 2)) ^ (((unsigned)rloc & 7u) << 4);
      ah[m] = *reinterpret_cast<const bf16x8*>(AsH + off);
      al[m] = *reinterpret_cast<const bf16x8*>(AsL + off);
    }
#pragma unroll
    for (int n = 0; n < 8; ++n) {
      const unsigned short* wp = Wt + (size_t)(n * 16 + lr) * EMB + koff;
      bf16x8 bh = *reinterpret_cast<const bf16x8*>(wp);
      bf16x8 bl = *reinterpret_cast<const bf16x8*>(wp + 128 * EMB);
#pragma unroll
      for (int m = 0; m < 2; ++m) {
        acc2[m][n] = __builtin_amdgcn_mfma_f32_16x16x32_bf16(ah[m], bh, acc2[m][n], 0, 0, 0);
        acc2[m][n] = __builtin_amdgcn_mfma_f32_16x16x32_bf16(al[m], bh, acc2[m][n], 0, 0, 0);
        acc2[m][n] = __builtin_amdgcn_mfma_f32_16x16x32_bf16(ah[m], bl, acc2[m][n], 0, 0, 0);
      }
    }
  }

#pragma unroll
  for (int n = 0; n < 8; ++n) {
    float bv = bias[n * 16 + lr];
#pragma unroll
    for (int m = 0; m < 2; ++m) {
#pragma unroll
      for (int r4 = 0; r4 < 4; ++r4) {
        int row = blockbase + rowloc + m * 16 + lg * 4 + r4;
        if (row < N)
          outp[(size_t)row * EMB + n * 16 + lr] = fmaxf(acc2[m][n][r4] + bv, 0.f);
      }
    }
  }
}

extern "C" void kernel_launch(void* const* d_in, const int* in_sizes, int n_in,
                              void* d_out, int out_size, void* d_ws, size_t ws_size,
                              hipStream_t stream) {
  const int*   x        = (const int*)d_in[0];
  const int*   eidx     = (const int*)d_in[1];
  const int*   eattr    = (const int*)d_in[2];
  const float* atom_emb = (const float*)d_in[3];
  const float* bond_emb = (const float*)d_in[4];
  const float* lin_W    = (const float*)d_in[5];
  const float* lin_b    = (const float*)d_in[6];
  float* out = (float*)d_out;

  const int N = in_sizes[0];
  const int E = in_sizes[1] / 2;
  const int L = in_sizes[5] / (EMB * EMB);
  const int BV = in_sizes[4] / EMB;
  const int* row = eidx;
  const int* col = eidx + E;

  const int NS = (E + (1 << HSTRIPE_LOG) - 1) >> HSTRIPE_LOG;  // edge stripes
  const int NR = (N + HRANGE - 1) / HRANGE;                    // node ranges

  char* ws = (char*)d_ws;
  size_t off = 0;
  auto alloc = [&](size_t bytes) {
    char* p = ws + off;
    off += (bytes + 255) & ~(size_t)255;
    return p;
  };
  float*          hbuf    = (float*)alloc((size_t)N * EMB * 4);
  unsigned short* Wt      = (unsigned short*)alloc((size_t)L * 256 * EMB * 2);
  unsigned short* degP    = (unsigned short*)alloc((size_t)NS * N * 2);
  unsigned short* cntP    = (unsigned short*)alloc((size_t)NS * N * 2);
  int*            cnt     = (int*)alloc((size_t)N * 4);
  int*            startp  = (int*)alloc((size_t)(N + 1) * 4);
  float*          dinv    = (float*)alloc((size_t)N * 4);
  int*            partial = (int*)alloc((size_t)1024 * 4);
  int*            ord     = (int*)alloc((size_t)E * 4);
  int2*           emeta   = (int2*)alloc((size_t)E * 8);
  (void)ws_size; (void)n_in; (void)out_size;

  int eb = (E + 255) / 256;
  int nb = (N + 255) / 256;
  dim3 hgrid(NS, NR);
  k_hist<<<hgrid, 256, 0, stream>>>(row, col, degP, cntP, ord, E, N);
  k_dinv<<<nb, 256, 0, stream>>>(degP, dinv, N, NS);
  k_colreduce<<<nb, 256, 0, stream>>>(cntP, cnt, N, NS);
  k_scan_local<<<nb, 256, 0, stream>>>(cnt, startp, partial, N);
  k_scan_part<<<1, 1024, 0, stream>>>(partial, nb);
  k_scan_add<<<nb, 256, 0, stream>>>(startp, partial, N, E);
  k_fill<<<eb, 256, 0, stream>>>(row, col, eattr, startp, cntP, ord, dinv, emeta, E, N);
  int wtot = L * EMB * EMB;
  k_wsplit<<<(wtot + 255) / 256, 256, 0, stream>>>(lin_W, Wt, wtot);

  int fb = (N + 127) / 128;
  // l=0: atom_emb[x] gathered directly (L2-resident) -> hbuf
  k_fused<1><<<fb, 256, 0, stream>>>(hbuf, x, atom_emb, startp, emeta, bond_emb,
                                     Wt, lin_b, hbuf, N, BV);
  float* hcur = hbuf;
  for (int l = 1; l < L; ++l) {
    float* hnext = (l == L - 1) ? out : ((hcur == hbuf) ? out : hbuf);
    k_fused<0><<<fb, 256, 0, stream>>>(hcur, x, atom_emb, startp, emeta, bond_emb,
                                       Wt + (size_t)l * 256 * EMB,
                                       lin_b + (size_t)l * EMB, hnext, N, BV);
    hcur = hnext;
  }
}

// Round 9
// 453.689 us; speedup vs baseline: 1.4644x; 1.4644x over previous
//
#include <hip/hip_runtime.h>

#define EMB 128
#define HRANGE 16384       // nodes per histogram range (64 KB LDS, packed cnt|deg)
#define HSTRIPE_LOG 13     // 8192 edges per stripe
#define UN 4

typedef __attribute__((ext_vector_type(8))) short bf16x8;
typedef __attribute__((ext_vector_type(4))) float f32x4;

__device__ inline unsigned short f2bf(float f) {
  unsigned u = __float_as_uint(f);
  return (unsigned short)((u + 0x7FFF + ((u >> 16) & 1)) >> 16);   // RNE
}
__device__ inline float bf2f(unsigned short s) {
  return __uint_as_float(((unsigned)s) << 16);
}

// ---------- CSR build via LDS histograms, packed cnt|deg (no global atomics) ----
__global__ __launch_bounds__(256) void k_hist(const int* __restrict__ row,
    const int* __restrict__ col, unsigned short* __restrict__ degP,
    unsigned short* __restrict__ cntP, int* __restrict__ ord, int E, int N) {
  __shared__ unsigned int hw[HRANGE];
  int s = blockIdx.x, r = blockIdx.y;
  int nlo = r * HRANGE;
  for (int t = threadIdx.x; t < HRANGE; t += 256) hw[t] = 0u;
  __syncthreads();
  int k0 = s << HSTRIPE_LOG;
  int k1 = min(E, k0 + (1 << HSTRIPE_LOG));
  for (int k = k0 + threadIdx.x; k < k1; k += 256) {
    int c = col[k] - nlo;
    if ((unsigned)c < HRANGE)
      ord[k] = (int)(atomicAdd(&hw[c], 1u) & 0xFFFFu);
    int rr = row[k] - nlo;
    if ((unsigned)rr < HRANGE)
      atomicAdd(&hw[rr], 0x10000u);
  }
  __syncthreads();
  for (int t = threadIdx.x; t < HRANGE; t += 256) {
    int node = nlo + t;
    if (node < N) {
      unsigned w = hw[t];
      cntP[(size_t)s * N + node] = (unsigned short)(w & 0xFFFFu);
      degP[(size_t)s * N + node] = (unsigned short)(w >> 16);
    }
  }
}

// exclusive prefix over stripes per node (in place, u16); cnt[i] = total
__global__ __launch_bounds__(256) void k_colreduce(unsigned short* __restrict__ cntP,
    int* __restrict__ cnt, int N, int ns) {
  int i = blockIdx.x * 256 + threadIdx.x;
  if (i < N) {
    int ssum = 0;
    for (int s = 0; s < ns; ++s) {
      int v = cntP[(size_t)s * N + i];
      cntP[(size_t)s * N + i] = (unsigned short)ssum;
      ssum += v;
    }
    cnt[i] = ssum;
  }
}

// deg[i] = sum of degP over stripes; dinv = rsqrt(max(deg,1))
__global__ __launch_bounds__(256) void k_dinv(const unsigned short* __restrict__ degP,
    float* __restrict__ dinv, int N, int ns) {
  int i = blockIdx.x * 256 + threadIdx.x;
  if (i < N) {
    int d = 0;
    for (int s = 0; s < ns; ++s) d += degP[(size_t)s * N + i];
    float df = (float)(d == 0 ? 1 : d);
    dinv[i] = 1.0f / sqrtf(df);
  }
}

// ---------- multi-block exclusive scan ----------
__global__ __launch_bounds__(256) void k_scan_local(const int* __restrict__ cnt,
    int* __restrict__ startp, int* __restrict__ partial, int N) {
  __shared__ int lds[256];
  int tid = threadIdx.x;
  int i = blockIdx.x * 256 + tid;
  int v = (i < N) ? cnt[i] : 0;
  lds[tid] = v;
  __syncthreads();
#pragma unroll
  for (int off = 1; off < 256; off <<= 1) {
    int t = (tid >= off) ? lds[tid - off] : 0;
    __syncthreads();
    lds[tid] += t;
    __syncthreads();
  }
  if (i < N) startp[i] = lds[tid] - v;
  if (tid == 255) partial[blockIdx.x] = lds[255];
}

__global__ void k_scan_part(int* __restrict__ partial, int nb) {
  __shared__ int lds[1024];
  int tid = threadIdx.x;
  int v = (tid < nb) ? partial[tid] : 0;
  lds[tid] = v;
  __syncthreads();
  for (int off = 1; off < 1024; off <<= 1) {
    int t = (tid >= off) ? lds[tid - off] : 0;
    __syncthreads();
    lds[tid] += t;
    __syncthreads();
  }
  if (tid < nb) partial[tid] = lds[tid] - v;
}

__global__ __launch_bounds__(256) void k_scan_add(int* __restrict__ startp,
    const int* __restrict__ partial, int N, int E) {
  int i = blockIdx.x * 256 + threadIdx.x;
  if (i < N) startp[i] += partial[blockIdx.x];
  if (i == 0) startp[N] = E;
}

__global__ __launch_bounds__(256) void k_fill(const int* __restrict__ row,
    const int* __restrict__ col, const int* __restrict__ attr,
    const int* __restrict__ startp, const unsigned short* __restrict__ cntP,
    const int* __restrict__ ord, const float* __restrict__ dinv,
    int2* __restrict__ emeta, int E, int N) {
  int k = blockIdx.x * 256 + threadIdx.x;
  if (k < E) {
    int r = row[k], c = col[k];
    int s = k >> HSTRIPE_LOG;
    int pos = startp[c] + (int)cntP[(size_t)s * N + c] + ord[k];
    int2 m;
    m.x = r | (attr[k] << 20);
    m.y = __float_as_int(dinv[r] * dinv[c]);
    emeta[pos] = m;
  }
}

// ---------- W split: Wt[l][ 0..127 ][k]=hi, Wt[l][128..255][k]=lo (col-major) ----
__global__ __launch_bounds__(256) void k_wsplit(const float* __restrict__ W,
    unsigned short* __restrict__ Wt, int total) {
  int t = blockIdx.x * 256 + threadIdx.x;   // t = (l*128 + k)*128 + n
  if (t >= total) return;
  int n = t & 127, k = (t >> 7) & 127, l = t >> 14;
  float v = W[t];
  unsigned short hi = f2bf(v);
  unsigned short lo = f2bf(v - bf2f(hi));
  size_t base = (size_t)l * 256 * EMB;
  Wt[base + (size_t)n * EMB + k] = hi;
  Wt[base + (size_t)(128 + n) * EMB + k] = lo;
}

// ---------- aggregation: one wave per node, 2 edges per gather instr ----------
// L0=1: gather atom_emb[x[src]] (both L2-resident) instead of materialized h.
template<int L0>
__global__ __launch_bounds__(256) void k_agg(const float* __restrict__ h,
    const int* __restrict__ xv, const float* __restrict__ atom_emb,
    const int* __restrict__ startp, const int2* __restrict__ emeta,
    const float* __restrict__ bond_emb, unsigned short* __restrict__ Ahi,
    unsigned short* __restrict__ Alo, int N, int BV) {
  __shared__ float eb_lds[16 * EMB];           // bond table, 8 KB
  for (int t = threadIdx.x; t < BV * (EMB / 4); t += 256)
    reinterpret_cast<float4*>(eb_lds)[t] =
        reinterpret_cast<const float4*>(bond_emb)[t];
  __syncthreads();

  int wave = threadIdx.x >> 6, lane = threadIdx.x & 63;
  int half = lane >> 5, sl = lane & 31;
  int node = blockIdx.x * 4 + wave;
  if (node >= N) return;
  int s = startp[node], e = startp[node + 1];
  float4 acc = make_float4(0.f, 0.f, 0.f, 0.f);
  int npair = (e - s + 1) >> 1;

  for (int step = 0; step < npair; step += UN) {
    int2 m[UN];
#pragma unroll
    for (int u = 0; u < UN; ++u) {
      int ep = s + 2 * (step + u) + half;
      m[u] = (ep < e) ? emeta[ep] : make_int2(0, 0);   // pad: w=+0 -> adds 0
    }
    float4 hv[UN];
#pragma unroll
    for (int u = 0; u < UN; ++u) {
      int src = m[u].x & 0xFFFFF;
      if constexpr (L0) {
        int xi = xv[src];
        hv[u] = *(reinterpret_cast<const float4*>(atom_emb + (size_t)xi * EMB) + sl);
      } else {
        hv[u] = *(reinterpret_cast<const float4*>(h + (size_t)src * EMB) + sl);
      }
    }
#pragma unroll
    for (int u = 0; u < UN; ++u) {
      float w = __int_as_float(m[u].y);
      float4 ev = *(reinterpret_cast<const float4*>(eb_lds + (m[u].x >> 20) * EMB) + sl);
      acc.x = fmaf(w * hv[u].x, ev.x, acc.x);
      acc.y = fmaf(w * hv[u].y, ev.y, acc.y);
      acc.z = fmaf(w * hv[u].z, ev.z, acc.z);
      acc.w = fmaf(w * hv[u].w, ev.w, acc.w);
    }
  }

  acc.x += __shfl_xor(acc.x, 32);
  acc.y += __shfl_xor(acc.y, 32);
  acc.z += __shfl_xor(acc.z, 32);
  acc.w += __shfl_xor(acc.w, 32);

  if (half == 0) {
    unsigned short h0 = f2bf(acc.x), h1 = f2bf(acc.y);
    unsigned short h2 = f2bf(acc.z), h3 = f2bf(acc.w);
    ushort4 hi4; hi4.x = h0; hi4.y = h1; hi4.z = h2; hi4.w = h3;
    ushort4 lo4;
    lo4.x = f2bf(acc.x - bf2f(h0));
    lo4.y = f2bf(acc.y - bf2f(h1));
    lo4.z = f2bf(acc.z - bf2f(h2));
    lo4.w = f2bf(acc.w - bf2f(h3));
    *(reinterpret_cast<ushort4*>(Ahi + (size_t)node * EMB) + sl) = hi4;
    *(reinterpret_cast<ushort4*>(Alo + (size_t)node * EMB) + sl) = lo4;
  }
}

// ---------- h_next = relu(split_bf16(agg) @ W + b) via MFMA ----------
__global__ __launch_bounds__(256) void k_gemm(const unsigned short* __restrict__ Ahi,
    const unsigned short* __restrict__ Alo, const unsigned short* __restrict__ Wt,
    const float* __restrict__ bias, float* __restrict__ outp, int M) {
  int wave = threadIdx.x >> 6, lane = threadIdx.x & 63;
  int lr = lane & 15, lg = lane >> 4;
  int rowbase = blockIdx.x * 128 + wave * 32;
  f32x4 acc[2][8];
#pragma unroll
  for (int m = 0; m < 2; ++m)
#pragma unroll
    for (int n = 0; n < 8; ++n) acc[m][n] = (f32x4){0.f, 0.f, 0.f, 0.f};

#pragma unroll
  for (int kb = 0; kb < 4; ++kb) {
    int koff = kb * 32 + lg * 8;
    bf16x8 ah[2], al[2];
#pragma unroll
    for (int m = 0; m < 2; ++m) {
      int r = rowbase + m * 16 + lr;
      if (r >= M) r = M - 1;                 // clamp; stores are guarded
      ah[m] = *reinterpret_cast<const bf16x8*>(Ahi + (size_t)r * EMB + koff);
      al[m] = *reinterpret_cast<const bf16x8*>(Alo + (size_t)r * EMB + koff);
    }
#pragma unroll
    for (int n = 0; n < 8; ++n) {
      const unsigned short* wp = Wt + (size_t)(n * 16 + lr) * EMB + koff;
      bf16x8 bh = *reinterpret_cast<const bf16x8*>(wp);
      bf16x8 bl = *reinterpret_cast<const bf16x8*>(wp + 128 * EMB);
#pragma unroll
      for (int m = 0; m < 2; ++m) {
        acc[m][n] = __builtin_amdgcn_mfma_f32_16x16x32_bf16(ah[m], bh, acc[m][n], 0, 0, 0);
        acc[m][n] = __builtin_amdgcn_mfma_f32_16x16x32_bf16(al[m], bh, acc[m][n], 0, 0, 0);
        acc[m][n] = __builtin_amdgcn_mfma_f32_16x16x32_bf16(ah[m], bl, acc[m][n], 0, 0, 0);
      }
    }
  }

#pragma unroll
  for (int n = 0; n < 8; ++n) {
    float bv = bias[n * 16 + lr];
#pragma unroll
    for (int m = 0; m < 2; ++m) {
#pragma unroll
      for (int r4 = 0; r4 < 4; ++r4) {
        int row = rowbase + m * 16 + lg * 4 + r4;
        if (row < M)
          outp[(size_t)row * EMB + n * 16 + lr] = fmaxf(acc[m][n][r4] + bv, 0.f);
      }
    }
  }
}

extern "C" void kernel_launch(void* const* d_in, const int* in_sizes, int n_in,
                              void* d_out, int out_size, void* d_ws, size_t ws_size,
                              hipStream_t stream) {
  const int*   x        = (const int*)d_in[0];
  const int*   eidx     = (const int*)d_in[1];
  const int*   eattr    = (const int*)d_in[2];
  const float* atom_emb = (const float*)d_in[3];
  const float* bond_emb = (const float*)d_in[4];
  const float* lin_W    = (const float*)d_in[5];
  const float* lin_b    = (const float*)d_in[6];
  float* out = (float*)d_out;

  const int N = in_sizes[0];
  const int E = in_sizes[1] / 2;
  const int L = in_sizes[5] / (EMB * EMB);
  const int BV = in_sizes[4] / EMB;
  const int* row = eidx;
  const int* col = eidx + E;

  const int NS = (E + (1 << HSTRIPE_LOG) - 1) >> HSTRIPE_LOG;  // edge stripes
  const int NR = (N + HRANGE - 1) / HRANGE;                    // node ranges

  char* ws = (char*)d_ws;
  size_t off = 0;
  auto alloc = [&](size_t bytes) {
    char* p = ws + off;
    off += (bytes + 255) & ~(size_t)255;
    return p;
  };
  float*          hbuf    = (float*)alloc((size_t)N * EMB * 4);
  unsigned short* Ahi     = (unsigned short*)alloc((size_t)N * EMB * 2);
  unsigned short* Alo     = (unsigned short*)alloc((size_t)N * EMB * 2);
  unsigned short* Wt      = (unsigned short*)alloc((size_t)L * 256 * EMB * 2);
  unsigned short* degP    = (unsigned short*)alloc((size_t)NS * N * 2);
  unsigned short* cntP    = (unsigned short*)alloc((size_t)NS * N * 2);
  int*            cnt     = (int*)alloc((size_t)N * 4);
  int*            startp  = (int*)alloc((size_t)(N + 1) * 4);
  float*          dinv    = (float*)alloc((size_t)N * 4);
  int*            partial = (int*)alloc((size_t)1024 * 4);
  int*            ord     = (int*)alloc((size_t)E * 4);
  int2*           emeta   = (int2*)alloc((size_t)E * 8);
  (void)ws_size; (void)n_in; (void)out_size;

  int eb = (E + 255) / 256;
  int nb = (N + 255) / 256;
  dim3 hgrid(NS, NR);
  k_hist<<<hgrid, 256, 0, stream>>>(row, col, degP, cntP, ord, E, N);
  k_dinv<<<nb, 256, 0, stream>>>(degP, dinv, N, NS);
  k_colreduce<<<nb, 256, 0, stream>>>(cntP, cnt, N, NS);
  k_scan_local<<<nb, 256, 0, stream>>>(cnt, startp, partial, N);
  k_scan_part<<<1, 1024, 0, stream>>>(partial, nb);
  k_scan_add<<<nb, 256, 0, stream>>>(startp, partial, N, E);
  k_fill<<<eb, 256, 0, stream>>>(row, col, eattr, startp, cntP, ord, dinv, emeta, E, N);
  int wtot = L * EMB * EMB;
  k_wsplit<<<(wtot + 255) / 256, 256, 0, stream>>>(lin_W, Wt, wtot);

  int ab = (N + 3) / 4;
  int gb = (N + 127) / 128;
  float* hcur = hbuf;
  for (int l = 0; l < L; ++l) {
    if (l == 0)
      k_agg<1><<<ab, 256, 0, stream>>>(hcur, x, atom_emb, startp, emeta, bond_emb,
                                       Ahi, Alo, N, BV);
    else
      k_agg<0><<<ab, 256, 0, stream>>>(hcur, x, atom_emb, startp, emeta, bond_emb,
                                       Ahi, Alo, N, BV);
    float* hnext = (l == L - 1) ? out : ((hcur == hbuf) ? out : hbuf);
    k_gemm<<<gb, 256, 0, stream>>>(Ahi, Alo, Wt + (size_t)l * 256 * EMB,
                                   lin_b + (size_t)l * EMB, hnext, N);
    hcur = hnext;
  }
}